// Round 8
// baseline (273.243 us; speedup 1.0000x reference)
//
#include <hip/hip_runtime.h>
#include <math.h>

#define DEV __device__ __forceinline__

typedef __attribute__((ext_vector_type(8))) short short8;
typedef __attribute__((ext_vector_type(4))) short short4v;
typedef __attribute__((ext_vector_type(4))) float f32x4;
typedef __attribute__((ext_vector_type(2))) unsigned uint2v;
typedef __attribute__((ext_vector_type(4))) unsigned uint4v;

// LDS row stride in shorts (272 B = 68 words; 68 mod 32 = 4 -> b128 reads
// land 2-way on banks = free per m136). MUST be a multiple of 8 shorts:
// SSTR=114 (r4/r5) gave 4-mod-16 ds_*_b128 addresses -- correct results but
// ~60% LDS-throughput penalty (116 -> 187 us) with conflicts reading 0.
#define SSTR 136
#define ROWB (16 * SSTR * 2)   // 4352 B per 16-row tile

DEV short f2bf(float f) {
    unsigned u = __builtin_bit_cast(unsigned, f);
    unsigned r = (u + 0x7fffu + ((u >> 16) & 1u)) >> 16;
    return (short)r;
}

#if __has_builtin(__builtin_amdgcn_cvt_pk_bf16_f32)
DEV unsigned pk2bf(float a, float b) {
    auto v = __builtin_amdgcn_cvt_pk_bf16_f32(a, b);
    return __builtin_bit_cast(unsigned, v);
}
#else
DEV unsigned pk2bf(float a, float b) {
    return ((unsigned)(unsigned short)f2bf(a)) |
           (((unsigned)(unsigned short)f2bf(b)) << 16);
}
#endif

// ---------------------------------------------------------------------------
// prep (weights only -- embT was eliminated in r8: fused_conv converts emb
// f32->bf16 in its staging loop, sampler pools in f32):
// blocks 0..237 = packing into MFMA A-frag order ([ks][fblk][lane]: per
// (ks,mt) a wave reads one contiguous 1 KB line); blocks 238/239 = gate
// weight transposes so the zg prologue reads coalesced.
// ---------------------------------------------------------------------------
__global__ __launch_bounds__(256) void prep_kernel(
    const float* __restrict__ c1w, const float* __restrict__ c2w,
    const float* __restrict__ liw, const float* __restrict__ c3w,
    const float* __restrict__ giw,
    short* __restrict__ A1, short* __restrict__ A2,
    short* __restrict__ A3, short* __restrict__ A4,
    float* __restrict__ giwT, float* __restrict__ w3T) {
    int bxg = blockIdx.x;
    if (bxg >= 238) {
        int t = threadIdx.x;
        if (bxg == 238) {
            for (int i = t; i < 10000; i += 256) {
                int f = i / 100, g = i % 100;           // giwT[f][g]
                giwT[f * 100 + g] = giw[g * 100 + f];
            }
        } else {
            for (int i = t; i < 10000; i += 256) {
                int h = i / 100, f = i % 100;           // w3T[h][f]
                w3T[h * 100 + f] = c3w[f * 200 + h];
            }
        }
        return;
    }
    if (threadIdx.x >= 64) return;
    int bx = bxg;
    const float* w; short* dst; int mode, lbx;
    if (bx < 70)       { w = c1w; dst = A1; mode = 0; lbx = bx; }
    else if (bx < 140) { w = c2w; dst = A2; mode = 0; lbx = bx - 70; }
    else if (bx < 210) { w = liw; dst = A3; mode = 0; lbx = bx - 140; }
    else               { w = c3w; dst = A4; mode = 1; lbx = bx - 210; }
    int lane = threadIdx.x;
    int f = lbx % 7 * 16 + (lane & 15);
    int kb = (lbx / 7) * 32 + (lane >> 4) * 8;
    short8 v;
#pragma unroll
    for (int j = 0; j < 8; ++j) {
        int kk = kb + j;
        float val = 0.f;
        if (f < 100) {
            if (mode == 0) {
                int oct = kk >> 3, dk = oct / 13;
                int c = (oct - 13 * dk) * 8 + (kk & 7);
                if (dk < 3 && c < 100) val = w[(f * 100 + c) * 3 + dk];
            } else {
                if (kk < 100) val = w[f * 200 + 100 + kk];
            }
        }
        v[j] = f2bf(val);
    }
    *(short8*)&dst[(lbx * 64 + lane) * 8] = v;
}

// ---------------------------------------------------------------------------
// One 3-tap conv pass, BALANCED tile (r0-proven): this wave owns mt
// [MTB,MTB+MT) x nt [NTB,NTB+NT). B-reads amortize over MT MFMAs, A-rows
// over NT. Accumulator init = bias. CLAMPL: the nt==4 tile reads clamped
// rows (feeds only discarded outputs; halo chain loc<=63 -> c2<=65 ->
// h<=67 -> e<=69 all real). EDGE: l-range zeroing only in bx 0/7.
// POOL: relu partial sums for l in [l0,l0+64) -> hpart_slot[112].
// ---------------------------------------------------------------------------
template<int MT, int NT, int MTB, int NTB, bool CLAMPL, bool POOL,
         bool TO_GLOBAL, bool EDGE>
DEV void ctap(const short* __restrict__ Ap, const short* s_src, short* s_dst,
              short* __restrict__ gout, const int* bofs, const int* bofs4,
              const float* __restrict__ bias, int row0l, int l0,
              float* __restrict__ hpart_slot, int lane) {
    const int q = lane >> 4, n = lane & 15;
    const f32x4 z4 = {0.f, 0.f, 0.f, 0.f};
    f32x4 acc[MT][NT];
#pragma unroll
    for (int mt = 0; mt < MT; ++mt) {
        int fb = (MTB + mt) * 16 + q * 4;
        f32x4 bs = (fb < 100) ? *(const f32x4*)&bias[fb] : z4;
#pragma unroll
        for (int nt = 0; nt < NT; ++nt) acc[mt][nt] = bs;
    }
#pragma unroll
    for (int ks = 0; ks < 10; ++ks) {
        short8 a[MT];
#pragma unroll
        for (int mt = 0; mt < MT; ++mt)
            a[mt] = *(const short8*)&Ap[(ks * 448 + (MTB + mt) * 64 + lane) * 8];
        const char* bp = (const char*)s_src + bofs[ks];
        short8 bf[NT];
#pragma unroll
        for (int nt = 0; nt < NT; ++nt) {
            if (CLAMPL && (NTB + nt) == 4)
                bf[nt] = *(const short8*)((const char*)s_src + bofs4[ks]);
            else
                bf[nt] = *(const short8*)(bp + (NTB + nt) * ROWB);
        }
#pragma unroll
        for (int mt = 0; mt < MT; ++mt)
#pragma unroll
            for (int nt = 0; nt < NT; ++nt)
                acc[mt][nt] = __builtin_amdgcn_mfma_f32_16x16x32_bf16(
                    a[mt], bf[nt], acc[mt][nt], 0, 0, 0);
    }
    f32x4 ps[MT];
    if constexpr (POOL) {
#pragma unroll
        for (int mt = 0; mt < MT; ++mt) ps[mt] = z4;
    }
#pragma unroll
    for (int nt = 0; nt < NT; ++nt) {
        const int j = (NTB + nt) * 16 + n;
        const int l = row0l + j;
        bool lok = true;
        if constexpr (EDGE) lok = ((unsigned)l < 512u);
        const bool pok = POOL && (l >= l0) && (l < l0 + 64);
#pragma unroll
        for (int mt = 0; mt < MT; ++mt) {
            const int fb = (MTB + mt) * 16 + q * 4;
            f32x4 v;
#pragma unroll
            for (int r = 0; r < 4; ++r) {
                v[r] = fmaxf(acc[mt][nt][r], 0.f);
                if constexpr (EDGE) v[r] = lok ? v[r] : 0.f;
            }
            if constexpr (POOL) {
                if (pok) {
#pragma unroll
                    for (int r = 0; r < 4; ++r) ps[mt][r] += v[r];
                }
            }
            uint2v pk;
            pk[0] = pk2bf(v[0], v[1]); pk[1] = pk2bf(v[2], v[3]);
            if constexpr (TO_GLOBAL) {
                *(uint2v*)&gout[j * 112 + fb] = pk;
            } else {
                if ((NTB + nt) < 4 || n < 6)      // store rows j < 70 only
                    *(uint2v*)&s_dst[j * SSTR + fb] = pk;
            }
        }
    }
    if constexpr (POOL) {
#pragma unroll
        for (int mt = 0; mt < MT; ++mt)
#pragma unroll
            for (int off = 1; off <= 8; off <<= 1)
#pragma unroll
                for (int r = 0; r < 4; ++r)
                    ps[mt][r] += __shfl_xor(ps[mt][r], off, 64);
        if (n == 0) {
#pragma unroll
            for (int mt = 0; mt < MT; ++mt)
                *(f32x4*)&hpart_slot[(MTB + mt) * 16 + q * 4] = ps[mt];
        }
    }
}

// ---------------------------------------------------------------------------
// Fused conv1 -> conv2 -> li, 64-wide l-tile, 256 threads (4 waves), grid
// (8,512) -- the proven structure. Staging now gathers DIRECTLY from emb f32
// and converts to bf16 in flight (cvt_pk), eliminating the embT
// materialization (22.4 MB write + read and 12.5K prep blocks). Staging =
// VGPR gather + ds_write (global_load_lds with scattered sources serializes
// the LDS-DMA: 3.6x regression, r2). Balanced wave tiles: wv0=(4,3)@(0,0)
// wv1=(4,2)@(0,3) wv2=(3,3)@(4,0) wv3=(3,2)@(4,3); li: NT=2 each @(0/4,0/2).
// Reg budget ~64 VGPR + 64 AGPR = 128/wave -> 4 waves/SIMD ceiling (r4).
// LDS 2*72*SSTR*2 = 39168 B.
// B-reads touch cols <= 103 only, so staging covers chunks c8 0..12 (cols
// 0..103) with 100..103 zeroed; cols 104+ are only ever WRITTEN (by pass
// epilogues) and never read.
// ---------------------------------------------------------------------------
__global__ __launch_bounds__(256, 4) void fused_conv_kernel(
    const int* __restrict__ xidx, const float* __restrict__ emb,
    const short* __restrict__ A1, const short* __restrict__ A2,
    const short* __restrict__ A3,
    const float* __restrict__ b1, const float* __restrict__ b2,
    const float* __restrict__ b3,
    short* __restrict__ locT, float* __restrict__ hpart) {
    extern __shared__ char smem[];
    short* s_e = (short*)smem;                    // [72][SSTR], later c2
    short* s_h = (short*)(smem + 72 * SSTR * 2);  // [72][SSTR]
    const int tid = threadIdx.x;
    const int b = blockIdx.y, bx = blockIdx.x, l0 = bx * 64;
    const int lane = tid & 63, wv = tid >> 6;
    const int q = lane >> 4, n = lane & 15;

    // stage e: 70 rows x 13 chunks of 8 cols, f32 -> bf16 in flight
#pragma unroll
    for (int p = 0; p < 4; ++p) {
        int idx = tid + p * 256;           // 0..1023, need 70*13 = 910
        int j = idx / 13, c8 = idx - j * 13;
        if (j < 70) {
            int lg = l0 - 3 + j;
            uint4v pk = {0, 0, 0, 0};
            if (lg >= 0 && lg < 512) {
                int row = xidx[b * 512 + lg];
                const float* er = &emb[(size_t)row * 100 + c8 * 8];
                f32x4 e0 = *(const f32x4*)er;
                pk[0] = pk2bf(e0[0], e0[1]);
                pk[1] = pk2bf(e0[2], e0[3]);
                if (c8 < 12) {                 // c8==12: cols 100..103 stay 0
                    f32x4 e1 = *(const f32x4*)(er + 4);
                    pk[2] = pk2bf(e1[0], e1[1]);
                    pk[3] = pk2bf(e1[2], e1[3]);
                }
            }
            *(uint4v*)&s_e[j * SSTR + c8 * 8] = pk;
        }
    }

    // per-lane B byte offsets for all 10 k-steps (row n+dk, col c0)
    int bofs[10], bofs4[10];
#pragma unroll
    for (int ks = 0; ks < 10; ++ks) {
        int oct = ks * 4 + q;
        int dk = (oct >= 39) ? 3 : (oct >= 26) ? 2 : (oct >= 13) ? 1 : 0;
        int c0 = (oct - 13 * dk) * 8;
        bofs[ks] = ((n + dk) * SSTR + c0) * 2;
        int r4 = 64 + n + dk; if (r4 > 69) r4 = 69;  // discarded rows only
        bofs4[ks] = (r4 * SSTR + c0) * 2;
    }
    float* hps = hpart + ((b * 8 + bx) * 2 + (wv & 1)) * 112;
    short* gouts = locT + ((size_t)b * 512 + l0) * 112;

    __syncthreads();
    const bool edge = (bx == 0) || (bx == 7);

#define PASS3T(Ap, SRC, DST, BIAS, R0L, PL, E)                                   \
    if (wv == 0)      ctap<4,3,0,0,false,PL,false,E>(Ap,SRC,DST,nullptr,bofs,bofs4,BIAS,R0L,l0,hps,lane); \
    else if (wv == 1) ctap<4,2,0,3,true, PL,false,E>(Ap,SRC,DST,nullptr,bofs,bofs4,BIAS,R0L,l0,hps,lane); \
    else if (wv == 2) ctap<3,3,4,0,false,PL,false,E>(Ap,SRC,DST,nullptr,bofs,bofs4,BIAS,R0L,l0,hps,lane); \
    else              ctap<3,2,4,3,true, PL,false,E>(Ap,SRC,DST,nullptr,bofs,bofs4,BIAS,R0L,l0,hps,lane);

    if (edge) {
        PASS3T(A1, s_e, s_h, b1, l0 - 2, true, true)
        __syncthreads();
        PASS3T(A2, s_h, s_e, b2, l0 - 1, false, true)
    } else {
        PASS3T(A1, s_e, s_h, b1, l0 - 2, true, false)
        __syncthreads();
        PASS3T(A2, s_h, s_e, b2, l0 - 1, false, false)
    }
    __syncthreads();
    // li: outputs l in [l0, l0+63] always valid
    if (wv == 0)      ctap<4,2,0,0,false,false,true,false>(A3,s_e,nullptr,gouts,bofs,bofs4,b3,l0,l0,hps,lane);
    else if (wv == 1) ctap<4,2,0,2,false,false,true,false>(A3,s_e,nullptr,gouts,bofs,bofs4,b3,l0,l0,hps,lane);
    else if (wv == 2) ctap<3,2,4,0,false,false,true,false>(A3,s_e,nullptr,gouts,bofs,bofs4,b3,l0,l0,hps,lane);
    else              ctap<3,2,4,2,false,false,true,false>(A3,s_e,nullptr,gouts,bofs,bofs4,b3,l0,l0,hps,lane);
#undef PASS3T
}

// ---------------------------------------------------------------------------
// conv3 tile (runtime NTB): 7 f-rows x 2 nt cols per wave, B-fragments
// straight from global (zero reuse -- each locT element read by exactly one
// lane of one wave; r7). Writes complete logits for its 32 columns.
// ---------------------------------------------------------------------------
DEV void c3t(const short* __restrict__ locB, float* s_part,
             const short* __restrict__ A4, const float* s_zg,
             const float* __restrict__ w4, int NTB, int lane) {
    const int q = lane >> 4, n = lane & 15;
    const f32x4 z4 = {0.f, 0.f, 0.f, 0.f};
    f32x4 acc[7][2];
#pragma unroll
    for (int mt = 0; mt < 7; ++mt) {
        int fb = mt * 16 + q * 4;
        f32x4 zgv = *(const f32x4*)&s_zg[fb];   // pad entries are 0
#pragma unroll
        for (int nt = 0; nt < 2; ++nt) acc[mt][nt] = zgv;
    }
#pragma unroll
    for (int ks = 0; ks < 4; ++ks) {
        short8 a[7];
#pragma unroll
        for (int mt = 0; mt < 7; ++mt)
            a[mt] = *(const short8*)&A4[(ks * 448 + mt * 64 + lane) * 8];
        int c0 = (ks * 4 + q) * 8;
        if (c0 > 104) c0 = 104;   // A zero for kappa>=100; cols 104.. are 0
        const short* bp = locB + n * 112 + c0;
        short8 bf[2];
#pragma unroll
        for (int nt = 0; nt < 2; ++nt)
            bf[nt] = *(const short8*)(bp + (NTB + nt) * 16 * 112);
#pragma unroll
        for (int mt = 0; mt < 7; ++mt)
#pragma unroll
            for (int nt = 0; nt < 2; ++nt)
                acc[mt][nt] = __builtin_amdgcn_mfma_f32_16x16x32_bf16(
                    a[mt], bf[nt], acc[mt][nt], 0, 0, 0);
    }
#pragma unroll
    for (int nt = 0; nt < 2; ++nt) {
        float part = 0.f;
#pragma unroll
        for (int mt = 0; mt < 7; ++mt) {
            const int fb = mt * 16 + q * 4;
            f32x4 w4v = (fb < 100) ? *(const f32x4*)&w4[fb] : z4;
#pragma unroll
            for (int r = 0; r < 4; ++r)
                part += fmaxf(acc[mt][nt][r], 0.f) * w4v[r];
        }
        part += __shfl_xor(part, 16, 64);
        part += __shfl_xor(part, 32, 64);
        if (q == 0) s_part[(NTB + nt) * 16 + n] = part;   // full logit
    }
}

// ---------------------------------------------------------------------------
// MERGED conv3+conv4+sampler+head: one 512-thread block per b. zg prologue
// once per b; 8 waves run conv3 as 2 tiles/round x 2 rounds into s_part[512];
// logits never leave LDS; then Gumbel softmax sampler (wave-local shuffle,
// wv<2 take 2 k's) + f32 pooled gather from emb + fc1 relu + sigmoid head.
// Kills one launch + gap + the 2 MB logits round-trip.
// ---------------------------------------------------------------------------
__global__ __launch_bounds__(512) void conv3_samp_kernel(
    const short* __restrict__ locT, const short* __restrict__ A4,
    const float* __restrict__ hpart, const float* __restrict__ giwT,
    const float* __restrict__ gi_b, const float* __restrict__ w3T,
    const float* __restrict__ b3, const float* __restrict__ w4,
    const float* __restrict__ b4,
    const float* __restrict__ u, const int* __restrict__ xidx,
    const float* __restrict__ emb,
    const float* __restrict__ f1w, const float* __restrict__ f1b,
    const float* __restrict__ hw, const float* __restrict__ hb,
    float* __restrict__ cs_out, float* __restrict__ out) {
    const float EPSV = 1.1920929e-07f;
    const float INVT = 1.f / 0.3f;
    int b = blockIdx.x, tid = threadIdx.x;
    int lane = tid & 63, wv = tid >> 6;   // 8 waves
    __shared__ float s_part[512];
    __shared__ float s_zg[112], s_hm[112], s_g[100];
    __shared__ float s_logT[512], s_cs[512];
    __shared__ int s_x[512];
    __shared__ float s_csw[8][512];
    __shared__ float s_acc[32][112];
    __shared__ float s_pool[112], s_h2[100], s_fin[8];

    s_x[tid] = xidx[b * 512 + tid];

    // zg prologue: hm = pooled h mean; g = relu(gi MLP); zg = b3 + w3.g
    if (tid < 112) {
        float a = 0.f;
#pragma unroll
        for (int s = 0; s < 16; ++s) a += hpart[(b * 16 + s) * 112 + tid];
        s_hm[tid] = a * (1.f / 512.f);
    }
    __syncthreads();
    if (tid < 100) {
        float a = gi_b[tid];
        for (int f = 0; f < 100; ++f) a += s_hm[f] * giwT[f * 100 + tid];
        s_g[tid] = fmaxf(a, 0.f);
    }
    __syncthreads();
    if (tid < 112) {
        float a = 0.f;
        if (tid < 100) {
            a = b3[tid];
            for (int h = 0; h < 100; ++h) a += s_g[h] * w3T[h * 100 + tid];
        }
        s_zg[tid] = a;
    }
    __syncthreads();

    // conv3: 4 l-tiles of 128; waves (wv>>2) pick tile parity, NTB=(wv&3)*2
    {
        const int t0 = wv >> 2;
        const int NTB = (wv & 3) * 2;
#pragma unroll
        for (int rr = 0; rr < 2; ++rr) {
            int t = rr * 2 + t0;
            const short* locB = locT + ((size_t)b * 512 + t * 128) * 112;
            c3t(locB, s_part + t * 128, A4, s_zg, w4, NTB, lane);
        }
    }
    __syncthreads();
    s_logT[tid] = (s_part[tid] + b4[0]) * INVT;
    __syncthreads();

    // wave-local softmax per k: waves 0,1 take 2 k's, waves 2-7 take 1
    const int nk = (wv < 2) ? 2 : 1;
    float csl[8];
#pragma unroll
    for (int i = 0; i < 8; ++i) csl[i] = 0.f;
    float lt[8];
#pragma unroll
    for (int i = 0; i < 8; ++i) lt[i] = s_logT[lane * 8 + i];
    for (int j = 0; j < nk; ++j) {
        int k = wv + 8 * j;
        f32x4 u0 = *(const f32x4*)&u[(b * 10 + k) * 512 + lane * 8];
        f32x4 u1 = *(const f32x4*)&u[(b * 10 + k) * 512 + lane * 8 + 4];
        float nz[8];
#pragma unroll
        for (int i = 0; i < 8; ++i) {
            float vv = (i < 4) ? u0[i] : u1[i - 4];
            vv = fminf(fmaxf(vv, EPSV), 1.f - EPSV);
            nz[i] = -__logf(-__logf(vv)) * INVT + lt[i];
        }
        float m = nz[0];
#pragma unroll
        for (int i = 1; i < 8; ++i) m = fmaxf(m, nz[i]);
#pragma unroll
        for (int off = 1; off <= 32; off <<= 1) m = fmaxf(m, __shfl_xor(m, off, 64));
        float e[8], s = 0.f;
#pragma unroll
        for (int i = 0; i < 8; ++i) { e[i] = __expf(nz[i] - m); s += e[i]; }
#pragma unroll
        for (int off = 1; off <= 32; off <<= 1) s += __shfl_xor(s, off, 64);
        float inv = 1.f / s;
#pragma unroll
        for (int i = 0; i < 8; ++i) csl[i] = fmaxf(csl[i], e[i] * inv);
    }
#pragma unroll
    for (int i = 0; i < 8; ++i) s_csw[wv][lane * 8 + i] = csl[i];
    __syncthreads();
    {
        float c = s_csw[0][tid];
#pragma unroll
        for (int w = 1; w < 8; ++w) c = fmaxf(c, s_csw[w][tid]);
        s_cs[tid] = c;
        cs_out[b * 512 + tid] = c;
    }
    __syncthreads();
    // pooled partial sums straight from emb f32: thread (jg, c8) covers
    // l = jg+32t, channels c8*8..+7 (c8=12 -> cols 96..99 only; cols >=100
    // don't exist)
    int jg = tid >> 4, c8 = tid & 15;   // jg 0..31
    if (c8 < 13) {
        f32x4 pa = {0.f, 0.f, 0.f, 0.f}, pb = {0.f, 0.f, 0.f, 0.f};
#pragma unroll 4
        for (int l = jg; l < 512; l += 32) {
            int row = s_x[l];
            float cv = s_cs[l];
            const float* er = &emb[(size_t)row * 100 + c8 * 8];
            f32x4 e0 = *(const f32x4*)er;
#pragma unroll
            for (int r = 0; r < 4; ++r) pa[r] += cv * e0[r];
            if (c8 < 12) {
                f32x4 e1 = *(const f32x4*)(er + 4);
#pragma unroll
                for (int r = 0; r < 4; ++r) pb[r] += cv * e1[r];
            }
        }
        *(f32x4*)&s_acc[jg][c8 * 8] = pa;
        *(f32x4*)&s_acc[jg][c8 * 8 + 4] = pb;
    }
    __syncthreads();
    if (tid < 100) {
        float p = 0.f;
#pragma unroll
        for (int g = 0; g < 32; ++g) p += s_acc[g][tid];
        s_pool[tid] = p * (1.f / 512.f);
    }
    __syncthreads();
    if (tid < 100) {
        float a = f1b[tid];
        for (int i = 0; i < 100; ++i) a += s_pool[i] * f1w[tid * 100 + i];
        s_h2[tid] = fmaxf(a, 0.f);
    }
    __syncthreads();
    float v = (tid < 100) ? s_h2[tid] * hw[tid] : 0.f;
#pragma unroll
    for (int off = 32; off >= 1; off >>= 1) v += __shfl_xor(v, off, 64);
    if (lane == 0) s_fin[wv] = v;
    __syncthreads();
    if (tid == 0) {
        float z = hb[0];
#pragma unroll
        for (int w = 0; w < 8; ++w) z += s_fin[w];
        out[b] = 1.f / (1.f + __expf(-z));
    }
}

// ---------------------------------------------------------------------------
extern "C" void kernel_launch(void* const* d_in, const int* in_sizes, int n_in,
                              void* d_out, int out_size, void* d_ws, size_t ws_size,
                              hipStream_t stream) {
    const int*   x   = (const int*)d_in[0];
    const float* u   = (const float*)d_in[1];
    const float* emb = (const float*)d_in[2];
    const float* c1w = (const float*)d_in[3];
    const float* c1b = (const float*)d_in[4];
    const float* giw = (const float*)d_in[5];
    const float* gib = (const float*)d_in[6];
    const float* c2w = (const float*)d_in[7];
    const float* c2b = (const float*)d_in[8];
    const float* liw = (const float*)d_in[9];
    const float* lib = (const float*)d_in[10];
    const float* c3w = (const float*)d_in[11];
    const float* c3b = (const float*)d_in[12];
    const float* c4w = (const float*)d_in[13];
    const float* c4b = (const float*)d_in[14];
    const float* f1w = (const float*)d_in[15];
    const float* f1b = (const float*)d_in[16];
    const float* hww = (const float*)d_in[17];
    const float* hbb = (const float*)d_in[18];
    float* out = (float*)d_out;

    char* ws = (char*)d_ws;
    short* locT   = (short*)(ws + 0);           // [512][512][112] bf16 (58.7 MB)
    short* A1     = (short*)(ws + 58720256);    // 10*448*16 B each
    short* A2     = (short*)(ws + 58791936);
    short* A3     = (short*)(ws + 58863616);
    short* A4     = (short*)(ws + 58935296);    // 4*448*16 B
    float* hpart  = (float*)(ws + 58963968);    // [512][8][2][112]
    float* giwT   = (float*)(ws + 62633984);    // [100][100]
    float* w3T    = (float*)(ws + 62673984);    // [100][100]

    prep_kernel<<<240, 256, 0, stream>>>(c1w, c2w, liw, c3w, giw,
                                         A1, A2, A3, A4, giwT, w3T);

    size_t smemA = (size_t)2 * 72 * SSTR * 2;            // 39168 B
    fused_conv_kernel<<<dim3(8, 512), 256, smemA, stream>>>(
        x, emb, A1, A2, A3, c1b, c2b, lib, locT, hpart);
    conv3_samp_kernel<<<512, 512, 0, stream>>>(
        locT, A4, hpart, giwT, gib, w3T, c3b, c4w, c4b,
        u, x, emb, f1w, f1b, hww, hbb, out + 512, out);
}

// Round 9
// 265.496 us; speedup vs baseline: 1.0292x; 1.0292x over previous
//
#include <hip/hip_runtime.h>
#include <math.h>

#define DEV __device__ __forceinline__

typedef __attribute__((ext_vector_type(8))) short short8;
typedef __attribute__((ext_vector_type(4))) short short4v;
typedef __attribute__((ext_vector_type(4))) float f32x4;
typedef __attribute__((ext_vector_type(2))) unsigned uint2v;

// LDS row stride in shorts (272 B = 68 words; 68 mod 32 = 4 -> b128 reads
// land 2-way on banks = free per m136). MUST be a multiple of 8 shorts:
// SSTR=114 (r4/r5) gave 4-mod-16 ds_*_b128 addresses -- correct results but
// ~60% LDS-throughput penalty (116 -> 187 us) with conflicts reading 0.
#define SSTR 136
#define ROWB (16 * SSTR * 2)   // 4352 B per 16-row tile

DEV short f2bf(float f) {
    unsigned u = __builtin_bit_cast(unsigned, f);
    unsigned r = (u + 0x7fffu + ((u >> 16) & 1u)) >> 16;
    return (short)r;
}

#if __has_builtin(__builtin_amdgcn_cvt_pk_bf16_f32)
DEV unsigned pk2bf(float a, float b) {
    auto v = __builtin_amdgcn_cvt_pk_bf16_f32(a, b);
    return __builtin_bit_cast(unsigned, v);
}
#else
DEV unsigned pk2bf(float a, float b) {
    return ((unsigned)(unsigned short)f2bf(a)) |
           (((unsigned)(unsigned short)f2bf(b)) << 16);
}
#endif

DEV float bfu(short s) {
    unsigned u = ((unsigned)(unsigned short)s) << 16;
    return __builtin_bit_cast(float, u);
}

// ---------------------------------------------------------------------------
// prep: blocks 0..12499 = emb cvt (f32 [V][100] -> bf16 [V][112], pad cols
// zeroed, 8 rows/block); blocks 12500..12737 = weight packing into MFMA
// A-frag order; blocks 12738/12739 = gate-weight transposes (giwT[f][t] =
// gi_w[t][f], w3T[h][f] = c3w[f][h]) so the zg prologue reads coalesced.
// ---------------------------------------------------------------------------
__global__ __launch_bounds__(256) void prep_kernel(
    const float* __restrict__ emb, short* __restrict__ embT,
    const float* __restrict__ c1w, const float* __restrict__ c2w,
    const float* __restrict__ liw, const float* __restrict__ c3w,
    const float* __restrict__ giw,
    short* __restrict__ A1, short* __restrict__ A2,
    short* __restrict__ A3, short* __restrict__ A4,
    float* __restrict__ giwT, float* __restrict__ w3T) {
    int bxg = blockIdx.x;
    if (bxg < 12500) {
        int t = threadIdx.x;
        int row = bxg * 8 + (t >> 5);
        int c4 = t & 31;
        if (c4 >= 28) return;
        short4v v = {0, 0, 0, 0};
        if (c4 < 25) {
            f32x4 e = *(const f32x4*)&emb[row * 100 + c4 * 4];
#pragma unroll
            for (int r = 0; r < 4; ++r) v[r] = f2bf(e[r]);
        }
        *(short4v*)&embT[row * 112 + c4 * 4] = v;
        return;
    }
    if (bxg >= 12738) {
        // transposes: 100x100 each, one block apiece
        int t = threadIdx.x;
        if (bxg == 12738) {
            for (int i = t; i < 10000; i += 256) {
                int f = i / 100, g = i % 100;           // giwT[f][g]
                giwT[f * 100 + g] = giw[g * 100 + f];
            }
        } else {
            for (int i = t; i < 10000; i += 256) {
                int h = i / 100, f = i % 100;           // w3T[h][f]
                w3T[h * 100 + f] = c3w[f * 200 + h];
            }
        }
        return;
    }
    if (threadIdx.x >= 64) return;
    int bx = bxg - 12500;
    const float* w; short* dst; int mode, lbx;
    if (bx < 70)       { w = c1w; dst = A1; mode = 0; lbx = bx; }
    else if (bx < 140) { w = c2w; dst = A2; mode = 0; lbx = bx - 70; }
    else if (bx < 210) { w = liw; dst = A3; mode = 0; lbx = bx - 140; }
    else               { w = c3w; dst = A4; mode = 1; lbx = bx - 210; }
    int lane = threadIdx.x;
    int f = lbx % 7 * 16 + (lane & 15);
    int kb = (lbx / 7) * 32 + (lane >> 4) * 8;
    short8 v;
#pragma unroll
    for (int j = 0; j < 8; ++j) {
        int kk = kb + j;
        float val = 0.f;
        if (f < 100) {
            if (mode == 0) {
                int oct = kk >> 3, dk = oct / 13;
                int c = (oct - 13 * dk) * 8 + (kk & 7);
                if (dk < 3 && c < 100) val = w[(f * 100 + c) * 3 + dk];
            } else {
                if (kk < 100) val = w[f * 200 + 100 + kk];
            }
        }
        v[j] = f2bf(val);
    }
    *(short8*)&dst[(lbx * 64 + lane) * 8] = v;
}

// ---------------------------------------------------------------------------
// One 3-tap conv pass, BALANCED tile (r0-proven): this wave owns mt
// [MTB,MTB+MT) x nt [NTB,NTB+NT). B-reads amortize over MT MFMAs, A-rows
// over NT. Accumulator init = bias. CLAMPL: the nt==4 tile reads clamped
// rows (feeds only discarded outputs; halo chain loc<=63 -> c2<=65 ->
// h<=67 -> e<=69 all real). EDGE: l-range zeroing only in bx 0/7.
// POOL: relu partial sums for l in [l0,l0+64) -> hpart_slot[112].
// ---------------------------------------------------------------------------
template<int MT, int NT, int MTB, int NTB, bool CLAMPL, bool POOL,
         bool TO_GLOBAL, bool EDGE>
DEV void ctap(const short* __restrict__ Ap, const short* s_src, short* s_dst,
              short* __restrict__ gout, const int* bofs, const int* bofs4,
              const float* __restrict__ bias, int row0l, int l0,
              float* __restrict__ hpart_slot, int lane) {
    const int q = lane >> 4, n = lane & 15;
    const f32x4 z4 = {0.f, 0.f, 0.f, 0.f};
    f32x4 acc[MT][NT];
#pragma unroll
    for (int mt = 0; mt < MT; ++mt) {
        int fb = (MTB + mt) * 16 + q * 4;
        f32x4 bs = (fb < 100) ? *(const f32x4*)&bias[fb] : z4;
#pragma unroll
        for (int nt = 0; nt < NT; ++nt) acc[mt][nt] = bs;
    }
#pragma unroll
    for (int ks = 0; ks < 10; ++ks) {
        short8 a[MT];
#pragma unroll
        for (int mt = 0; mt < MT; ++mt)
            a[mt] = *(const short8*)&Ap[(ks * 448 + (MTB + mt) * 64 + lane) * 8];
        const char* bp = (const char*)s_src + bofs[ks];
        short8 bf[NT];
#pragma unroll
        for (int nt = 0; nt < NT; ++nt) {
            if (CLAMPL && (NTB + nt) == 4)
                bf[nt] = *(const short8*)((const char*)s_src + bofs4[ks]);
            else
                bf[nt] = *(const short8*)(bp + (NTB + nt) * ROWB);
        }
#pragma unroll
        for (int mt = 0; mt < MT; ++mt)
#pragma unroll
            for (int nt = 0; nt < NT; ++nt)
                acc[mt][nt] = __builtin_amdgcn_mfma_f32_16x16x32_bf16(
                    a[mt], bf[nt], acc[mt][nt], 0, 0, 0);
    }
    f32x4 ps[MT];
    if constexpr (POOL) {
#pragma unroll
        for (int mt = 0; mt < MT; ++mt) ps[mt] = z4;
    }
#pragma unroll
    for (int nt = 0; nt < NT; ++nt) {
        const int j = (NTB + nt) * 16 + n;
        const int l = row0l + j;
        bool lok = true;
        if constexpr (EDGE) lok = ((unsigned)l < 512u);
        const bool pok = POOL && (l >= l0) && (l < l0 + 64);
#pragma unroll
        for (int mt = 0; mt < MT; ++mt) {
            const int fb = (MTB + mt) * 16 + q * 4;
            f32x4 v;
#pragma unroll
            for (int r = 0; r < 4; ++r) {
                v[r] = fmaxf(acc[mt][nt][r], 0.f);
                if constexpr (EDGE) v[r] = lok ? v[r] : 0.f;
            }
            if constexpr (POOL) {
                if (pok) {
#pragma unroll
                    for (int r = 0; r < 4; ++r) ps[mt][r] += v[r];
                }
            }
            uint2v pk;
            pk[0] = pk2bf(v[0], v[1]); pk[1] = pk2bf(v[2], v[3]);
            if constexpr (TO_GLOBAL) {
                *(uint2v*)&gout[j * 112 + fb] = pk;
            } else {
                if ((NTB + nt) < 4 || n < 6)      // store rows j < 70 only
                    *(uint2v*)&s_dst[j * SSTR + fb] = pk;
            }
        }
    }
    if constexpr (POOL) {
#pragma unroll
        for (int mt = 0; mt < MT; ++mt)
#pragma unroll
            for (int off = 1; off <= 8; off <<= 1)
#pragma unroll
                for (int r = 0; r < 4; ++r)
                    ps[mt][r] += __shfl_xor(ps[mt][r], off, 64);
        if (n == 0) {
#pragma unroll
            for (int mt = 0; mt < MT; ++mt)
                *(f32x4*)&hpart_slot[(MTB + mt) * 16 + q * 4] = ps[mt];
        }
    }
}

// ---------------------------------------------------------------------------
// Fused conv1 -> conv2 -> li, 64-wide l-tile, 256 threads (4 waves), grid
// (8,512) -- the proven structure (frozen; 100.2-101.0 us across sessions).
// Staging = VGPR gather + ds_write from bf16 embT (f32-direct staging costs
// +12 us: FETCH 42.5->69 MB, r8; global_load_lds with scattered sources
// serializes the LDS-DMA: 3.6x regression, r2). Balanced wave tiles:
// wv0=(4,3)@(0,0) wv1=(4,2)@(0,3) wv2=(3,3)@(4,0) wv3=(3,2)@(4,3);
// li: NT=2 each @(0/4,0/2). Reg budget ~64 VGPR + 64 AGPR = 128/wave ->
// 4 waves/SIMD ceiling (min-waves=5 spilled, r4). LDS 2*72*SSTR*2 = 39168 B.
// ---------------------------------------------------------------------------
__global__ __launch_bounds__(256, 4) void fused_conv_kernel(
    const int* __restrict__ xidx, const short* __restrict__ embT,
    const short* __restrict__ A1, const short* __restrict__ A2,
    const short* __restrict__ A3,
    const float* __restrict__ b1, const float* __restrict__ b2,
    const float* __restrict__ b3,
    short* __restrict__ locT, float* __restrict__ hpart) {
    extern __shared__ char smem[];
    short* s_e = (short*)smem;                    // [72][SSTR], later c2
    short* s_h = (short*)(smem + 72 * SSTR * 2);  // [72][SSTR]
    const int tid = threadIdx.x;
    const int b = blockIdx.y, bx = blockIdx.x, l0 = bx * 64;
    const int lane = tid & 63, wv = tid >> 6;
    const int q = lane >> 4, n = lane & 15;

    // stage e: 70 rows x 14 b128 chunks (virtual 16-grid; c8>=14 skipped)
#pragma unroll
    for (int p = 0; p < 5; ++p) {
        int idx = tid + p * 256;           // 0..1279, need j<70
        int j = idx >> 4, c8 = idx & 15;
        if (j < 70 && c8 < 14) {
            int lg = l0 - 3 + j;
            short8 v = {0, 0, 0, 0, 0, 0, 0, 0};
            if (lg >= 0 && lg < 512) {
                int row = xidx[b * 512 + lg];
                v = *(const short8*)&embT[row * 112 + c8 * 8];
            }
            *(short8*)&s_e[j * SSTR + c8 * 8] = v;
        }
    }

    // per-lane B byte offsets for all 10 k-steps (row n+dk, col c0)
    int bofs[10], bofs4[10];
#pragma unroll
    for (int ks = 0; ks < 10; ++ks) {
        int oct = ks * 4 + q;
        int dk = (oct >= 39) ? 3 : (oct >= 26) ? 2 : (oct >= 13) ? 1 : 0;
        int c0 = (oct - 13 * dk) * 8;
        bofs[ks] = ((n + dk) * SSTR + c0) * 2;
        int r4 = 64 + n + dk; if (r4 > 69) r4 = 69;  // discarded rows only
        bofs4[ks] = (r4 * SSTR + c0) * 2;
    }
    float* hps = hpart + ((b * 8 + bx) * 2 + (wv & 1)) * 112;
    short* gouts = locT + ((size_t)b * 512 + l0) * 112;

    __syncthreads();
    const bool edge = (bx == 0) || (bx == 7);

#define PASS3T(Ap, SRC, DST, BIAS, R0L, PL, E)                                   \
    if (wv == 0)      ctap<4,3,0,0,false,PL,false,E>(Ap,SRC,DST,nullptr,bofs,bofs4,BIAS,R0L,l0,hps,lane); \
    else if (wv == 1) ctap<4,2,0,3,true, PL,false,E>(Ap,SRC,DST,nullptr,bofs,bofs4,BIAS,R0L,l0,hps,lane); \
    else if (wv == 2) ctap<3,3,4,0,false,PL,false,E>(Ap,SRC,DST,nullptr,bofs,bofs4,BIAS,R0L,l0,hps,lane); \
    else              ctap<3,2,4,3,true, PL,false,E>(Ap,SRC,DST,nullptr,bofs,bofs4,BIAS,R0L,l0,hps,lane);

    if (edge) {
        PASS3T(A1, s_e, s_h, b1, l0 - 2, true, true)
        __syncthreads();
        PASS3T(A2, s_h, s_e, b2, l0 - 1, false, true)
    } else {
        PASS3T(A1, s_e, s_h, b1, l0 - 2, true, false)
        __syncthreads();
        PASS3T(A2, s_h, s_e, b2, l0 - 1, false, false)
    }
    __syncthreads();
    // li: outputs l in [l0, l0+63] always valid
    if (wv == 0)      ctap<4,2,0,0,false,false,true,false>(A3,s_e,nullptr,gouts,bofs,bofs4,b3,l0,l0,hps,lane);
    else if (wv == 1) ctap<4,2,0,2,false,false,true,false>(A3,s_e,nullptr,gouts,bofs,bofs4,b3,l0,l0,hps,lane);
    else if (wv == 2) ctap<3,2,4,0,false,false,true,false>(A3,s_e,nullptr,gouts,bofs,bofs4,b3,l0,l0,hps,lane);
    else              ctap<3,2,4,2,false,false,true,false>(A3,s_e,nullptr,gouts,bofs,bofs4,b3,l0,l0,hps,lane);
#undef PASS3T
}

// ---------------------------------------------------------------------------
// conv3 (1x1, loc half) + conv4 -> logits, zg prologue folded in. NO LDS
// STAGING: ownership analysis shows each locT element is read by exactly one
// lane of one wave (column-band waves own disjoint rows; (ks,q) octets cover
// disjoint cols) -- zero reuse, so B-fragments are read STRAIGHT FROM GLOBAL
// (each wave load = 16 rows x 64 contiguous bytes = full cache lines).
// zg prologue reads transposed giwT/w3T -> coalesced.
// ---------------------------------------------------------------------------
template<int NTB>
DEV void c3tile(const short* __restrict__ locB, float* s_part,
                const short* __restrict__ A4, const float* s_zg,
                const float* __restrict__ w4, int lane) {
    const int q = lane >> 4, n = lane & 15;
    const f32x4 z4 = {0.f, 0.f, 0.f, 0.f};
    f32x4 acc[7][2];
#pragma unroll
    for (int mt = 0; mt < 7; ++mt) {
        int fb = mt * 16 + q * 4;
        f32x4 zgv = *(const f32x4*)&s_zg[fb];   // pad entries are 0
#pragma unroll
        for (int nt = 0; nt < 2; ++nt) acc[mt][nt] = zgv;
    }
#pragma unroll
    for (int ks = 0; ks < 4; ++ks) {
        short8 a[7];
#pragma unroll
        for (int mt = 0; mt < 7; ++mt)
            a[mt] = *(const short8*)&A4[(ks * 448 + mt * 64 + lane) * 8];
        int c0 = (ks * 4 + q) * 8;
        if (c0 > 104) c0 = 104;   // A zero for kappa>=100; cols 104.. are 0
        const short* bp = locB + n * 112 + c0;
        short8 bf[2];
#pragma unroll
        for (int nt = 0; nt < 2; ++nt)
            bf[nt] = *(const short8*)(bp + (NTB + nt) * 16 * 112);
#pragma unroll
        for (int mt = 0; mt < 7; ++mt)
#pragma unroll
            for (int nt = 0; nt < 2; ++nt)
                acc[mt][nt] = __builtin_amdgcn_mfma_f32_16x16x32_bf16(
                    a[mt], bf[nt], acc[mt][nt], 0, 0, 0);
    }
#pragma unroll
    for (int nt = 0; nt < 2; ++nt) {
        float part = 0.f;
#pragma unroll
        for (int mt = 0; mt < 7; ++mt) {
            const int fb = mt * 16 + q * 4;
            f32x4 w4v = (fb < 100) ? *(const f32x4*)&w4[fb] : z4;
#pragma unroll
            for (int r = 0; r < 4; ++r)
                part += fmaxf(acc[mt][nt][r], 0.f) * w4v[r];
        }
        part += __shfl_xor(part, 16, 64);
        part += __shfl_xor(part, 32, 64);
        if (q == 0) s_part[(NTB + nt) * 16 + n] = part;   // full logit
    }
}

__global__ __launch_bounds__(256, 4) void conv3_logits_kernel(
    const short* __restrict__ locT, const short* __restrict__ A4,
    const float* __restrict__ hpart, const float* __restrict__ giwT,
    const float* __restrict__ gi_b, const float* __restrict__ w3T,
    const float* __restrict__ b3, const float* __restrict__ w4,
    const float* __restrict__ b4, float* __restrict__ logits) {
    __shared__ float s_part[128];
    __shared__ float s_zg[112];
    __shared__ float s_hm[112];
    __shared__ float s_g[100];
    const int tid = threadIdx.x;
    const int b = blockIdx.y, l0r = blockIdx.x * 128;
    const int lane = tid & 63, wv = tid >> 6;

    // zg prologue: hm = pooled h mean; g = relu(gi MLP); zg = b3 + w3.g
    if (tid < 112) {
        float a = 0.f;
#pragma unroll
        for (int s = 0; s < 16; ++s) a += hpart[(b * 16 + s) * 112 + tid];
        s_hm[tid] = a * (1.f / 512.f);
    }
    __syncthreads();
    if (tid < 100) {
        float a = gi_b[tid];
        for (int f = 0; f < 100; ++f) a += s_hm[f] * giwT[f * 100 + tid];
        s_g[tid] = fmaxf(a, 0.f);
    }
    __syncthreads();
    if (tid < 112) {
        float a = 0.f;
        if (tid < 100) {
            a = b3[tid];
            for (int h = 0; h < 100; ++h) a += s_g[h] * w3T[h * 100 + tid];
        }
        s_zg[tid] = a;
    }
    __syncthreads();

    const short* locB = locT + ((size_t)b * 512 + l0r) * 112;
    if (wv == 0)      c3tile<0>(locB, s_part, A4, s_zg, w4, lane);
    else if (wv == 1) c3tile<2>(locB, s_part, A4, s_zg, w4, lane);
    else if (wv == 2) c3tile<4>(locB, s_part, A4, s_zg, w4, lane);
    else              c3tile<6>(locB, s_part, A4, s_zg, w4, lane);
    __syncthreads();
    if (tid < 128)
        logits[b * 512 + l0r + tid] = s_part[tid] + b4[0];
}

// ---------------------------------------------------------------------------
// Fused sampler + distil head, one block per b, 512 THREADS (8 waves).
// Wave wv handles k = wv, wv+8 (<10) with wave-local shuffle softmax. Merge
// via LDS max, then pooled gather (bf16 embT, 16 l-iters/thread), fc1 relu,
// sigmoid head.
// ---------------------------------------------------------------------------
__global__ __launch_bounds__(512) void samp_head_kernel(
    const float* __restrict__ u, const float* __restrict__ logits,
    const int* __restrict__ xidx, const short* __restrict__ embT,
    const float* __restrict__ f1w, const float* __restrict__ f1b,
    const float* __restrict__ hw, const float* __restrict__ hb,
    float* __restrict__ cs_out, float* __restrict__ out) {
    const float EPSV = 1.1920929e-07f;
    const float INVT = 1.f / 0.3f;
    int b = blockIdx.x, tid = threadIdx.x;
    int lane = tid & 63, wv = tid >> 6;   // 8 waves
    __shared__ float s_logT[512], s_cs[512];
    __shared__ int s_x[512];
    __shared__ float s_csw[8][512];
    __shared__ float s_acc[32][112];
    __shared__ float s_pool[112], s_h2[100], s_fin[8];
    if (tid < 512) {
        s_logT[tid] = logits[b * 512 + tid] * INVT;
        s_x[tid] = xidx[b * 512 + tid];
    }
    __syncthreads();
    // wave-local softmax per k: waves 0,1 take 2 k's, waves 2-7 take 1
    const int nk = (wv < 2) ? 2 : 1;
    float csl[8];
#pragma unroll
    for (int i = 0; i < 8; ++i) csl[i] = 0.f;
    float lt[8];
#pragma unroll
    for (int i = 0; i < 8; ++i) lt[i] = s_logT[lane * 8 + i];
    for (int j = 0; j < nk; ++j) {
        int k = wv + 8 * j;
        f32x4 u0 = *(const f32x4*)&u[(b * 10 + k) * 512 + lane * 8];
        f32x4 u1 = *(const f32x4*)&u[(b * 10 + k) * 512 + lane * 8 + 4];
        float nz[8];
#pragma unroll
        for (int i = 0; i < 8; ++i) {
            float vv = (i < 4) ? u0[i] : u1[i - 4];
            vv = fminf(fmaxf(vv, EPSV), 1.f - EPSV);
            nz[i] = -__logf(-__logf(vv)) * INVT + lt[i];
        }
        float m = nz[0];
#pragma unroll
        for (int i = 1; i < 8; ++i) m = fmaxf(m, nz[i]);
#pragma unroll
        for (int off = 1; off <= 32; off <<= 1) m = fmaxf(m, __shfl_xor(m, off, 64));
        float e[8], s = 0.f;
#pragma unroll
        for (int i = 0; i < 8; ++i) { e[i] = __expf(nz[i] - m); s += e[i]; }
#pragma unroll
        for (int off = 1; off <= 32; off <<= 1) s += __shfl_xor(s, off, 64);
        float inv = 1.f / s;
#pragma unroll
        for (int i = 0; i < 8; ++i) csl[i] = fmaxf(csl[i], e[i] * inv);
    }
#pragma unroll
    for (int i = 0; i < 8; ++i) s_csw[wv][lane * 8 + i] = csl[i];
    __syncthreads();
    if (tid < 512) {
        float c = s_csw[0][tid];
#pragma unroll
        for (int w = 1; w < 8; ++w) c = fmaxf(c, s_csw[w][tid]);
        s_cs[tid] = c;
        cs_out[b * 512 + tid] = c;
    }
    __syncthreads();
    // pooled partial sums: thread (jg, c8) covers l = jg+32t, channels c8*8..+7
    int jg = tid >> 4, c8 = tid & 15;   // jg 0..31
    if (c8 < 14) {
        f32x4 pa = {0.f, 0.f, 0.f, 0.f}, pb = {0.f, 0.f, 0.f, 0.f};
#pragma unroll 4
        for (int l = jg; l < 512; l += 32) {
            int row = s_x[l];
            float cv = s_cs[l];
            short8 e8 = *(const short8*)&embT[(size_t)row * 112 + c8 * 8];
#pragma unroll
            for (int r = 0; r < 4; ++r) {
                pa[r] += cv * bfu(e8[r]);
                pb[r] += cv * bfu(e8[4 + r]);
            }
        }
        *(f32x4*)&s_acc[jg][c8 * 8] = pa;
        *(f32x4*)&s_acc[jg][c8 * 8 + 4] = pb;
    }
    __syncthreads();
    if (tid < 112) {
        float p = 0.f;
#pragma unroll
        for (int g = 0; g < 32; ++g) p += s_acc[g][tid];
        s_pool[tid] = p * (1.f / 512.f);
    }
    __syncthreads();
    if (tid < 100) {
        float a = f1b[tid];
        for (int i = 0; i < 100; ++i) a += s_pool[i] * f1w[tid * 100 + i];
        s_h2[tid] = fmaxf(a, 0.f);
    }
    __syncthreads();
    float v = (tid < 100) ? s_h2[tid] * hw[tid] : 0.f;
#pragma unroll
    for (int off = 32; off >= 1; off >>= 1) v += __shfl_xor(v, off, 64);
    if (lane == 0) s_fin[wv] = v;
    __syncthreads();
    if (tid == 0) {
        float z = hb[0];
#pragma unroll
        for (int w = 0; w < 8; ++w) z += s_fin[w];
        out[b] = 1.f / (1.f + __expf(-z));
    }
}

// ---------------------------------------------------------------------------
extern "C" void kernel_launch(void* const* d_in, const int* in_sizes, int n_in,
                              void* d_out, int out_size, void* d_ws, size_t ws_size,
                              hipStream_t stream) {
    const int*   x   = (const int*)d_in[0];
    const float* u   = (const float*)d_in[1];
    const float* emb = (const float*)d_in[2];
    const float* c1w = (const float*)d_in[3];
    const float* c1b = (const float*)d_in[4];
    const float* giw = (const float*)d_in[5];
    const float* gib = (const float*)d_in[6];
    const float* c2w = (const float*)d_in[7];
    const float* c2b = (const float*)d_in[8];
    const float* liw = (const float*)d_in[9];
    const float* lib = (const float*)d_in[10];
    const float* c3w = (const float*)d_in[11];
    const float* c3b = (const float*)d_in[12];
    const float* c4w = (const float*)d_in[13];
    const float* c4b = (const float*)d_in[14];
    const float* f1w = (const float*)d_in[15];
    const float* f1b = (const float*)d_in[16];
    const float* hww = (const float*)d_in[17];
    const float* hbb = (const float*)d_in[18];
    float* out = (float*)d_out;

    char* ws = (char*)d_ws;
    short* locT   = (short*)(ws + 0);           // [512][512][112] bf16 (58.7 MB)
    short* embT   = (short*)(ws + 58720256);    // [100000][112] bf16 (22.4 MB)
    short* A1     = (short*)(ws + 81120256);    // 10*448*16 B each
    short* A2     = (short*)(ws + 81191936);
    short* A3     = (short*)(ws + 81263616);
    short* A4     = (short*)(ws + 81335296);    // 4*448*16 B
    float* logits = (float*)(ws + 81593344);    // [512][512]
    float* hpart  = (float*)(ws + 82641920);    // [512][8][2][112]
    float* giwT   = (float*)(ws + 86311936);    // [100][100]
    float* w3T    = (float*)(ws + 86351936);    // [100][100]

    prep_kernel<<<12740, 256, 0, stream>>>(emb, embT, c1w, c2w, liw, c3w, giw,
                                           A1, A2, A3, A4, giwT, w3T);

    size_t smemA = (size_t)2 * 72 * SSTR * 2;            // 39168 B
    fused_conv_kernel<<<dim3(8, 512), 256, smemA, stream>>>(
        x, embT, A1, A2, A3, c1b, c2b, lib, locT, hpart);
    conv3_logits_kernel<<<dim3(4, 512), 256, 0, stream>>>(
        locT, A4, hpart, giwT, gib, w3T, c3b, c4w, c4b, logits);
    samp_head_kernel<<<512, 512, 0, stream>>>(
        u, logits, x, embT, f1w, f1b, hww, hbb, out + 512, out);
}